// Round 2
// baseline (523.758 us; speedup 1.0000x reference)
//
#include <hip/hip_runtime.h>

#define E_EDGES 320000
#define NN 20000
#define HID 128

typedef __attribute__((ext_vector_type(8))) short short8;
typedef __attribute__((ext_vector_type(4))) float f32x4;

__device__ __forceinline__ unsigned short f2b(float f) {
  unsigned u = __builtin_bit_cast(unsigned, f);
  u += 0x7fffu + ((u >> 16) & 1u);
  return (unsigned short)(u >> 16);
}

// ---------------- weight prepack: f32 [K][128] -> bf16 MFMA-fragment order ---
// dst[((kt*8 + ntg)*64 + lane)*8 + r] = W[kt*32 + (lane>>4)*8 + r][ntg*16 + (lane&15)]
__global__ void prepack_k(const float* __restrict__ Wce1, const float* __restrict__ Wce2,
                          const float* __restrict__ Ws1,  const float* __restrict__ Ws2,
                          const float* __restrict__ Wpe2, const float* __restrict__ Wpe1,
                          unsigned short* __restrict__ dst) {
  int i = blockIdx.x * 256 + threadIdx.x;          // grid covers exactly 102400
  const float* W; int Ksrc, base;
  if (i < 32768)      { W = Wce1; Ksrc = 256; base = 0; }
  else if (i < 49152) { W = Wce2; Ksrc = 128; base = 32768; }
  else if (i < 65536) { W = Ws1;  Ksrc = 128; base = 49152; }
  else if (i < 81920) { W = Ws2;  Ksrc = 128; base = 65536; }
  else if (i < 98304) { W = Wpe2; Ksrc = 128; base = 81920; }
  else                { W = Wpe1; Ksrc = 18;  base = 98304; }
  int j = i - base;
  int r = j & 7, lane = (j >> 3) & 63, ntg = (j >> 9) & 7, kt = j >> 12;
  int sk = kt * 32 + ((lane >> 4) << 3) + r;
  int sn = (ntg << 4) + (lane & 15);
  float v = (sk < Ksrc) ? W[sk * HID + sn] : 0.0f;
  dst[i] = f2b(v);
}

// ---------------- per-edge geometry + segment-sum atomics ---------------------
__global__ void edge_geom_k(const int* __restrict__ erow, const int* __restrict__ ecol,
                            const float* __restrict__ coord,
                            float* __restrict__ nf, float* __restrict__ cnt,
                            float* __restrict__ cdn) {
  int i = blockIdx.x * 256 + threadIdx.x;
  if (i >= E_EDGES) return;
  int r = erow[i], c = ecol[i];
  float dx = coord[r*3+0] - coord[c*3+0];
  float dy = coord[r*3+1] - coord[c*3+1];
  float dz = coord[r*3+2] - coord[c*3+2];
  float r2 = dx*dx + dy*dy + dz*dz;
  float dn = sqrtf(r2);
  float invn = 1.0f / (dn + 1e-8f);
  cdn[i*3+0] = dx*invn; cdn[i*3+1] = dy*invn; cdn[i*3+2] = dz*invn;
  float inv = 1.0f / dn;
  float w3 = inv*inv*inv, w4 = w3*inv, w5 = w4*inv;
  float* p = nf + r*9;
  atomicAdd(p+0, w3*dx); atomicAdd(p+1, w3*dy); atomicAdd(p+2, w3*dz);
  atomicAdd(p+3, w4*dx); atomicAdd(p+4, w4*dy); atomicAdd(p+5, w4*dz);
  atomicAdd(p+6, w5*dx); atomicAdd(p+7, w5*dy); atomicAdd(p+8, w5*dz);
  atomicAdd(cnt + r, 1.0f);
}

// ---------------- per-node normalize -----------------------------------------
__global__ void node_norm_k(const float* __restrict__ nf, const float* __restrict__ cnt,
                            float* __restrict__ nvecs) {
  int n = blockIdx.x * 256 + threadIdx.x;
  if (n >= NN) return;
  float cinv = 1.0f / fmaxf(cnt[n], 1.0f);
  #pragma unroll
  for (int a = 0; a < 3; a++) {
    float x = nf[n*9+a*3+0]*cinv, y = nf[n*9+a*3+1]*cinv, z = nf[n*9+a*3+2]*cinv;
    float nm = sqrtf(x*x + y*y + z*z);
    float s = 1.0f / (nm + 1e-8f);
    nvecs[n*9+a*3+0] = x*s; nvecs[n*9+a*3+1] = y*s; nvecs[n*9+a*3+2] = z*s;
  }
}

// ---------------- fused edge MLP: one INDEPENDENT wave per 16 edges -----------
// No __syncthreads anywhere: each wave's DS ops are program-ordered, and its
// 16x136 T-buffer is private to the wave.
#define TS 136   // 272B row stride: 16B-aligned, !=0 mod 128B -> even b128 banks
#define PS 40    // pos_in row stride (80B)

template <int NKT>
__device__ __forceinline__ void gemm_lds(const unsigned short* __restrict__ T, int stride,
                                         const unsigned short* __restrict__ wpL,
                                         const float* __restrict__ bias,
                                         int lane, int cl, int kg, f32x4 (&acc)[8]) {
  #pragma unroll
  for (int nt = 0; nt < 8; nt++) {
    float b = bias[nt*16 + cl];
    acc[nt] = f32x4{b, b, b, b};
  }
  #pragma unroll
  for (int kt = 0; kt < NKT; kt++) {
    short8 af = *reinterpret_cast<const short8*>(T + cl*stride + kt*32 + kg*8);
    #pragma unroll
    for (int nt = 0; nt < 8; nt++) {
      short8 bf = *reinterpret_cast<const short8*>(wpL + (((kt*8 + nt)*64) + lane)*8);
      acc[nt] = __builtin_amdgcn_mfma_f32_16x16x32_bf16(af, bf, acc[nt], 0, 0, 0);
    }
  }
}

__device__ __forceinline__ void silu_to_T(f32x4 (&acc)[8], unsigned short* __restrict__ T,
                                          int cl, int kg) {
  #pragma unroll
  for (int nt = 0; nt < 8; nt++)
    #pragma unroll
    for (int g = 0; g < 4; g++) {
      float x = acc[nt][g];
      float s = x / (1.0f + __expf(-x));
      T[(kg*4 + g)*TS + nt*16 + cl] = f2b(s);
    }
}

__launch_bounds__(256, 2)
__global__ void fused_k(const int* __restrict__ erow, const int* __restrict__ ecol,
                        const float* __restrict__ h, const float* __restrict__ coord,
                        const float* __restrict__ nvecs,
                        const unsigned short* __restrict__ wp,
                        const float* __restrict__ b1,  const float* __restrict__ b2,
                        const float* __restrict__ bs1, const float* __restrict__ bs2,
                        const float* __restrict__ bp1, const float* __restrict__ bp2,
                        const float* __restrict__ watt, const float* __restrict__ batt,
                        float* __restrict__ out0, float* __restrict__ chem_o,
                        float* __restrict__ pos_o) {
  __shared__ unsigned short sT[4][16 * TS];
  __shared__ unsigned short sPin[4][16 * PS];

  const int tid  = threadIdx.x;
  const int lane = tid & 63;
  const int wv   = tid >> 6;
  const int cl   = lane & 15;
  const int kg   = lane >> 4;
  const int e0   = blockIdx.x * 64 + wv * 16;   // this wave's 16 edges

  unsigned short* T   = sT[wv];
  unsigned short* Pin = sPin[wv];

  const int er = erow[e0 + cl];
  const int ec = ecol[e0 + cl];

  // ---- geometry -> pos_in (lanes kg==0 compute edge cl fully) ----
  if (kg == 0) {
    float dx = coord[er*3+0] - coord[ec*3+0];
    float dy = coord[er*3+1] - coord[ec*3+1];
    float dz = coord[er*3+2] - coord[ec*3+2];
    float r2 = dx*dx + dy*dy + dz*dz;
    #pragma unroll
    for (int a = 0; a < 3; a++) {
      float s = nvecs[er*9+a*3+0]*nvecs[ec*9+a*3+0]
              + nvecs[er*9+a*3+1]*nvecs[ec*9+a*3+1]
              + nvecs[er*9+a*3+2]*nvecs[ec*9+a*3+2];
      Pin[cl*PS + a] = f2b(s);
    }
    float t = 1.0f;
    #pragma unroll
    for (int s = 0; s < 15; s++) {
      Pin[cl*PS + 3 + s] = f2b(__expf(r2 * (-0.5f / t)));
      t *= 2.25f;
    }
    #pragma unroll
    for (int k = 18; k < 32; k++) Pin[cl*PS + k] = 0;
  }

  f32x4 acc[8];

  // ---- ce1: A = [h[row] | h[col]] gathered straight into fragments ----
  {
    #pragma unroll
    for (int nt = 0; nt < 8; nt++) {
      float b = b1[nt*16 + cl];
      acc[nt] = f32x4{b, b, b, b};
    }
    #pragma unroll
    for (int kt = 0; kt < 8; kt++) {
      int node = (kt < 4) ? er : ec;
      const float* hp = h + (size_t)node * HID + (kt & 3)*32 + kg*8;
      float4 v0 = *reinterpret_cast<const float4*>(hp);
      float4 v1 = *reinterpret_cast<const float4*>(hp + 4);
      short8 af;
      af[0] = (short)f2b(v0.x); af[1] = (short)f2b(v0.y);
      af[2] = (short)f2b(v0.z); af[3] = (short)f2b(v0.w);
      af[4] = (short)f2b(v1.x); af[5] = (short)f2b(v1.y);
      af[6] = (short)f2b(v1.z); af[7] = (short)f2b(v1.w);
      #pragma unroll
      for (int nt = 0; nt < 8; nt++) {
        short8 bf = *reinterpret_cast<const short8*>(wp + (((kt*8 + nt)*64) + lane)*8);
        acc[nt] = __builtin_amdgcn_mfma_f32_16x16x32_bf16(af, bf, acc[nt], 0, 0, 0);
      }
    }
    silu_to_T(acc, T, cl, kg);
  }

  // ---- ce2: chem (f32 global + bf16 back into T) ----
  gemm_lds<4>(T, TS, wp + 32768, b2, lane, cl, kg, acc);
  #pragma unroll
  for (int nt = 0; nt < 8; nt++)
    #pragma unroll
    for (int g = 0; g < 4; g++) {
      float x = acc[nt][g];
      chem_o[(size_t)(e0 + kg*4 + g) * HID + nt*16 + cl] = x;
      T[(kg*4 + g)*TS + nt*16 + cl] = f2b(x);
    }

  // ---- s1: silu -> T ----
  gemm_lds<4>(T, TS, wp + 49152, bs1, lane, cl, kg, acc);
  silu_to_T(acc, T, cl, kg);

  // ---- s2: keep in regs ----
  f32x4 accS[8];
  gemm_lds<4>(T, TS, wp + 65536, bs2, lane, cl, kg, accS);

  // ---- pe1 (K=32 padded): silu -> T ----
  gemm_lds<1>(Pin, PS, wp + 98304, bp1, lane, cl, kg, acc);
  silu_to_T(acc, T, cl, kg);

  // ---- pe2: pos out; o = s2 * pos ----
  gemm_lds<4>(T, TS, wp + 81920, bp2, lane, cl, kg, acc);
  #pragma unroll
  for (int nt = 0; nt < 8; nt++)
    #pragma unroll
    for (int g = 0; g < 4; g++) {
      float p = acc[nt][g];
      pos_o[(size_t)(e0 + kg*4 + g) * HID + nt*16 + cl] = p;
      accS[nt][g] *= p;                 // accS now holds o
    }

  // ---- attention: per-row dot via shfl within the 16-lane column group ----
  float ba = batt[0];
  float av[4];
  #pragma unroll
  for (int g = 0; g < 4; g++) {
    float s = 0.0f;
    #pragma unroll
    for (int nt = 0; nt < 8; nt++) s += accS[nt][g] * watt[nt*16 + cl];
    s += __shfl_xor(s, 1);
    s += __shfl_xor(s, 2);
    s += __shfl_xor(s, 4);
    s += __shfl_xor(s, 8);
    av[g] = 1.0f / (1.0f + __expf(-(s + ba)));
  }
  #pragma unroll
  for (int nt = 0; nt < 8; nt++)
    #pragma unroll
    for (int g = 0; g < 4; g++)
      out0[(size_t)(e0 + kg*4 + g) * HID + nt*16 + cl] = accS[nt][g] * av[g];
}

// ---------------- launcher ----------------------------------------------------
extern "C" void kernel_launch(void* const* d_in, const int* in_sizes, int n_in,
                              void* d_out, int out_size, void* d_ws, size_t ws_size,
                              hipStream_t stream) {
  (void)in_sizes; (void)n_in; (void)out_size; (void)ws_size;
  const float* h     = (const float*)d_in[0];
  const float* coord = (const float*)d_in[1];
  const int*   edges = (const int*)d_in[2];
  const float* W_ce1 = (const float*)d_in[3];  const float* b_ce1 = (const float*)d_in[4];
  const float* W_ce2 = (const float*)d_in[5];  const float* b_ce2 = (const float*)d_in[6];
  const float* W_pe1 = (const float*)d_in[7];  const float* b_pe1 = (const float*)d_in[8];
  const float* W_pe2 = (const float*)d_in[9];  const float* b_pe2 = (const float*)d_in[10];
  const float* W_s1  = (const float*)d_in[11]; const float* b_s1  = (const float*)d_in[12];
  const float* W_s2  = (const float*)d_in[13]; const float* b_s2  = (const float*)d_in[14];
  const float* W_att = (const float*)d_in[15]; const float* b_att = (const float*)d_in[16];

  float* out  = (float*)d_out;
  float* chem = out  + (size_t)E_EDGES * HID;
  float* pos  = chem + (size_t)E_EDGES * HID;
  float* cdn  = pos  + (size_t)E_EDGES * HID;

  float* nf    = (float*)d_ws;              // [NN*9]
  float* cnt   = nf + NN * 9;               // [NN]
  float* nvecs = cnt + NN;                  // [NN*9]
  unsigned short* wpack = (unsigned short*)(nvecs + NN * 9);  // 102400 bf16

  hipMemsetAsync(nf, 0, (size_t)(NN * 10) * sizeof(float), stream);
  prepack_k<<<400, 256, 0, stream>>>(W_ce1, W_ce2, W_s1, W_s2, W_pe2, W_pe1, wpack);
  edge_geom_k<<<(E_EDGES + 255) / 256, 256, 0, stream>>>(edges, edges + E_EDGES, coord,
                                                         nf, cnt, cdn);
  node_norm_k<<<(NN + 255) / 256, 256, 0, stream>>>(nf, cnt, nvecs);
  fused_k<<<E_EDGES / 64, 256, 0, stream>>>(edges, edges + E_EDGES, h, coord, nvecs, wpack,
                                            b_ce1, b_ce2, b_s1, b_s2, b_pe1, b_pe2,
                                            W_att, b_att, out, chem, pos);
}

// Round 3
// 467.613 us; speedup vs baseline: 1.1201x; 1.1201x over previous
//
#include <hip/hip_runtime.h>

#define E_EDGES 320000
#define NN 20000
#define HID 128
#define TS 136   // LDS T-tile stride (bf16 elems): 272B == 16 mod 128 -> spread banks

typedef __attribute__((ext_vector_type(8))) short short8;
typedef __attribute__((ext_vector_type(4))) float f32x4;
typedef __attribute__((ext_vector_type(8))) unsigned short us8;

__device__ __forceinline__ unsigned short f2b(float f) {
  unsigned u = __builtin_bit_cast(unsigned, f);
  u += 0x7fffu + ((u >> 16) & 1u);
  return (unsigned short)(u >> 16);
}
__device__ __forceinline__ float silu_f(float x) { return x / (1.0f + __expf(-x)); }

// ---------------- weight prepack: f32 [K][128] -> bf16 MFMA-fragment order ---
// dst[((kt*8 + ntg)*64 + lane)*8 + r] = W[kt*32 + (lane>>4)*8 + r][ntg*16 + (lane&15)]
__global__ void prepack_k(const float* __restrict__ Wce1, const float* __restrict__ Wce2,
                          const float* __restrict__ Ws1,  const float* __restrict__ Ws2,
                          const float* __restrict__ Wpe2, const float* __restrict__ Wpe1,
                          unsigned short* __restrict__ dst) {
  int i = blockIdx.x * 256 + threadIdx.x;          // grid covers exactly 102400
  const float* W; int Ksrc, base;
  if (i < 32768)      { W = Wce1; Ksrc = 256; base = 0; }
  else if (i < 49152) { W = Wce2; Ksrc = 128; base = 32768; }
  else if (i < 65536) { W = Ws1;  Ksrc = 128; base = 49152; }
  else if (i < 81920) { W = Ws2;  Ksrc = 128; base = 65536; }
  else if (i < 98304) { W = Wpe2; Ksrc = 128; base = 81920; }
  else                { W = Wpe1; Ksrc = 18;  base = 98304; }
  int j = i - base;
  int r = j & 7, lane = (j >> 3) & 63, ntg = (j >> 9) & 7, kt = j >> 12;
  int sk = kt * 32 + ((lane >> 4) << 3) + r;
  int sn = (ntg << 4) + (lane & 15);
  float v = (sk < Ksrc) ? W[sk * HID + sn] : 0.0f;
  dst[i] = f2b(v);
}

// ---------------- per-edge geometry + segment-sum atomics + radial table -----
__global__ void edge_geom_k(const int* __restrict__ erow, const int* __restrict__ ecol,
                            const float* __restrict__ coord,
                            float* __restrict__ nf, float* __restrict__ cnt,
                            float* __restrict__ cdn, unsigned short* __restrict__ rad16) {
  int i = blockIdx.x * 256 + threadIdx.x;
  if (i >= E_EDGES) return;
  int r = erow[i], c = ecol[i];
  float dx = coord[r*3+0] - coord[c*3+0];
  float dy = coord[r*3+1] - coord[c*3+1];
  float dz = coord[r*3+2] - coord[c*3+2];
  float r2 = dx*dx + dy*dy + dz*dz;
  float dn = sqrtf(r2);
  float invn = 1.0f / (dn + 1e-8f);
  cdn[i*3+0] = dx*invn; cdn[i*3+1] = dy*invn; cdn[i*3+2] = dz*invn;

  unsigned short rv[16];
  float t = 1.0f;
  #pragma unroll
  for (int s = 0; s < 15; s++) { rv[s] = f2b(__expf(r2 * (-0.5f / t))); t *= 2.25f; }
  rv[15] = 0;
  us8 lo, hi;
  #pragma unroll
  for (int k = 0; k < 8; k++) { lo[k] = rv[k]; hi[k] = rv[8+k]; }
  *reinterpret_cast<us8*>(rad16 + (size_t)i*16)     = lo;
  *reinterpret_cast<us8*>(rad16 + (size_t)i*16 + 8) = hi;

  float inv = 1.0f / dn;
  float w3 = inv*inv*inv, w4 = w3*inv, w5 = w4*inv;
  float* p = nf + r*9;
  atomicAdd(p+0, w3*dx); atomicAdd(p+1, w3*dy); atomicAdd(p+2, w3*dz);
  atomicAdd(p+3, w4*dx); atomicAdd(p+4, w4*dy); atomicAdd(p+5, w4*dz);
  atomicAdd(p+6, w5*dx); atomicAdd(p+7, w5*dy); atomicAdd(p+8, w5*dz);
  atomicAdd(cnt + r, 1.0f);
}

// ---------------- per-node normalize -----------------------------------------
__global__ void node_norm_k(const float* __restrict__ nf, const float* __restrict__ cnt,
                            float* __restrict__ nvecs) {
  int n = blockIdx.x * 256 + threadIdx.x;
  if (n >= NN) return;
  float cinv = 1.0f / fmaxf(cnt[n], 1.0f);
  #pragma unroll
  for (int a = 0; a < 3; a++) {
    float x = nf[n*9+a*3+0]*cinv, y = nf[n*9+a*3+1]*cinv, z = nf[n*9+a*3+2]*cinv;
    float nm = sqrtf(x*x + y*y + z*z);
    float s = 1.0f / (nm + 1e-8f);
    nvecs[n*9+a*3+0] = x*s; nvecs[n*9+a*3+1] = y*s; nvecs[n*9+a*3+2] = z*s;
  }
}

// ---------------- chem kernel: ce1 + ce2, 32 edges per wave -------------------
__global__ __launch_bounds__(256) void chem_k(
    const int* __restrict__ erow, const int* __restrict__ ecol,
    const float* __restrict__ h, const unsigned short* __restrict__ wp,
    const float* __restrict__ b1, const float* __restrict__ b2,
    float* __restrict__ chem_o) {
  __shared__ unsigned short sT[4][32 * TS];
  const int tid = threadIdx.x, lane = tid & 63, wv = tid >> 6;
  const int cl = lane & 15, kg = lane >> 4;
  const int e0 = (blockIdx.x * 4 + wv) * 32;
  unsigned short* T = sT[wv];

  int er[2], ec[2];
  er[0] = erow[e0 + cl];      ec[0] = ecol[e0 + cl];
  er[1] = erow[e0 + 16 + cl]; ec[1] = ecol[e0 + 16 + cl];

  f32x4 acc[2][8];
  #pragma unroll
  for (int nt = 0; nt < 8; nt++) {
    float b = b1[nt*16 + cl];
    acc[0][nt] = f32x4{b,b,b,b}; acc[1][nt] = f32x4{b,b,b,b};
  }
  #pragma unroll
  for (int kt = 0; kt < 8; kt++) {
    short8 bf[8];
    #pragma unroll
    for (int nt = 0; nt < 8; nt++)
      bf[nt] = *reinterpret_cast<const short8*>(wp + ((kt*8 + nt)*64 + lane)*8);
    #pragma unroll
    for (int rt = 0; rt < 2; rt++) {
      int node = (kt < 4) ? er[rt] : ec[rt];
      const float* hp = h + (size_t)node * HID + (kt & 3)*32 + kg*8;
      float4 v0 = *reinterpret_cast<const float4*>(hp);
      float4 v1 = *reinterpret_cast<const float4*>(hp + 4);
      short8 af;
      af[0]=(short)f2b(v0.x); af[1]=(short)f2b(v0.y); af[2]=(short)f2b(v0.z); af[3]=(short)f2b(v0.w);
      af[4]=(short)f2b(v1.x); af[5]=(short)f2b(v1.y); af[6]=(short)f2b(v1.z); af[7]=(short)f2b(v1.w);
      #pragma unroll
      for (int nt = 0; nt < 8; nt++)
        acc[rt][nt] = __builtin_amdgcn_mfma_f32_16x16x32_bf16(af, bf[nt], acc[rt][nt], 0, 0, 0);
    }
  }
  #pragma unroll
  for (int rt = 0; rt < 2; rt++)
    #pragma unroll
    for (int nt = 0; nt < 8; nt++)
      #pragma unroll
      for (int g = 0; g < 4; g++)
        T[(rt*16 + kg*4 + g)*TS + nt*16 + cl] = f2b(silu_f(acc[rt][nt][g]));

  // ce2 (wave-private T: DS ops are program-ordered, no barrier)
  #pragma unroll
  for (int nt = 0; nt < 8; nt++) {
    float b = b2[nt*16 + cl];
    acc[0][nt] = f32x4{b,b,b,b}; acc[1][nt] = f32x4{b,b,b,b};
  }
  #pragma unroll
  for (int kt = 0; kt < 4; kt++) {
    short8 bf[8];
    #pragma unroll
    for (int nt = 0; nt < 8; nt++)
      bf[nt] = *reinterpret_cast<const short8*>(wp + 32768 + ((kt*8 + nt)*64 + lane)*8);
    #pragma unroll
    for (int rt = 0; rt < 2; rt++) {
      short8 af = *reinterpret_cast<const short8*>(T + (rt*16 + cl)*TS + kt*32 + kg*8);
      #pragma unroll
      for (int nt = 0; nt < 8; nt++)
        acc[rt][nt] = __builtin_amdgcn_mfma_f32_16x16x32_bf16(af, bf[nt], acc[rt][nt], 0, 0, 0);
    }
  }
  #pragma unroll
  for (int rt = 0; rt < 2; rt++)
    #pragma unroll
    for (int nt = 0; nt < 8; nt++)
      #pragma unroll
      for (int g = 0; g < 4; g++)
        chem_o[(size_t)(e0 + rt*16 + kg*4 + g) * HID + nt*16 + cl] = acc[rt][nt][g];
}

// ---------------- sim+pos kernel: s1+s2+pe1+pe2+att, 32 edges per wave --------
__global__ __launch_bounds__(256) void simpos_k(
    const int* __restrict__ erow, const int* __restrict__ ecol,
    const float* __restrict__ chem_f, const unsigned short* __restrict__ rad16,
    const float* __restrict__ nvecs, const unsigned short* __restrict__ wp,
    const float* __restrict__ bs1, const float* __restrict__ bs2,
    const float* __restrict__ bp1, const float* __restrict__ bp2,
    const float* __restrict__ watt, const float* __restrict__ batt,
    float* __restrict__ out0, float* __restrict__ pos_o) {
  __shared__ unsigned short sT[4][32 * TS];
  const int tid = threadIdx.x, lane = tid & 63, wv = tid >> 6;
  const int cl = lane & 15, kg = lane >> 4;
  const int e0 = (blockIdx.x * 4 + wv) * 32;
  unsigned short* T = sT[wv];

  // ---- s1: A = chem (f32, streamed) ----
  f32x4 acc[2][8];
  #pragma unroll
  for (int nt = 0; nt < 8; nt++) {
    float b = bs1[nt*16 + cl];
    acc[0][nt] = f32x4{b,b,b,b}; acc[1][nt] = f32x4{b,b,b,b};
  }
  #pragma unroll
  for (int kt = 0; kt < 4; kt++) {
    short8 bf[8];
    #pragma unroll
    for (int nt = 0; nt < 8; nt++)
      bf[nt] = *reinterpret_cast<const short8*>(wp + 49152 + ((kt*8 + nt)*64 + lane)*8);
    #pragma unroll
    for (int rt = 0; rt < 2; rt++) {
      const float* cp = chem_f + (size_t)(e0 + rt*16 + cl) * HID + kt*32 + kg*8;
      float4 v0 = *reinterpret_cast<const float4*>(cp);
      float4 v1 = *reinterpret_cast<const float4*>(cp + 4);
      short8 af;
      af[0]=(short)f2b(v0.x); af[1]=(short)f2b(v0.y); af[2]=(short)f2b(v0.z); af[3]=(short)f2b(v0.w);
      af[4]=(short)f2b(v1.x); af[5]=(short)f2b(v1.y); af[6]=(short)f2b(v1.z); af[7]=(short)f2b(v1.w);
      #pragma unroll
      for (int nt = 0; nt < 8; nt++)
        acc[rt][nt] = __builtin_amdgcn_mfma_f32_16x16x32_bf16(af, bf[nt], acc[rt][nt], 0, 0, 0);
    }
  }
  #pragma unroll
  for (int rt = 0; rt < 2; rt++)
    #pragma unroll
    for (int nt = 0; nt < 8; nt++)
      #pragma unroll
      for (int g = 0; g < 4; g++)
        T[(rt*16 + kg*4 + g)*TS + nt*16 + cl] = f2b(silu_f(acc[rt][nt][g]));

  // ---- s2 -> accS (held) ----
  f32x4 accS[2][8];
  #pragma unroll
  for (int nt = 0; nt < 8; nt++) {
    float b = bs2[nt*16 + cl];
    accS[0][nt] = f32x4{b,b,b,b}; accS[1][nt] = f32x4{b,b,b,b};
  }
  #pragma unroll
  for (int kt = 0; kt < 4; kt++) {
    short8 bf[8];
    #pragma unroll
    for (int nt = 0; nt < 8; nt++)
      bf[nt] = *reinterpret_cast<const short8*>(wp + 65536 + ((kt*8 + nt)*64 + lane)*8);
    #pragma unroll
    for (int rt = 0; rt < 2; rt++) {
      short8 af = *reinterpret_cast<const short8*>(T + (rt*16 + cl)*TS + kt*32 + kg*8);
      #pragma unroll
      for (int nt = 0; nt < 8; nt++)
        accS[rt][nt] = __builtin_amdgcn_mfma_f32_16x16x32_bf16(af, bf[nt], accS[rt][nt], 0, 0, 0);
    }
  }

  // ---- pe1: pin = [nprod(3) | radial(15) | pad] assembled in-register ----
  us8 r0[2], r1[2];
  #pragma unroll
  for (int rt = 0; rt < 2; rt++) {
    r0[rt] = *reinterpret_cast<const us8*>(rad16 + (size_t)(e0 + rt*16 + cl)*16);
    r1[rt] = *reinterpret_cast<const us8*>(rad16 + (size_t)(e0 + rt*16 + cl)*16 + 8);
  }
  float np[2][3];
  if (kg == 0) {
    #pragma unroll
    for (int rt = 0; rt < 2; rt++) {
      int er_ = erow[e0 + rt*16 + cl], ec_ = ecol[e0 + rt*16 + cl];
      #pragma unroll
      for (int a = 0; a < 3; a++)
        np[rt][a] = nvecs[er_*9+a*3+0]*nvecs[ec_*9+a*3+0]
                  + nvecs[er_*9+a*3+1]*nvecs[ec_*9+a*3+1]
                  + nvecs[er_*9+a*3+2]*nvecs[ec_*9+a*3+2];
    }
  }
  #pragma unroll
  for (int nt = 0; nt < 8; nt++) {
    float b = bp1[nt*16 + cl];
    acc[0][nt] = f32x4{b,b,b,b}; acc[1][nt] = f32x4{b,b,b,b};
  }
  {
    short8 bf[8];
    #pragma unroll
    for (int nt = 0; nt < 8; nt++)
      bf[nt] = *reinterpret_cast<const short8*>(wp + 98304 + (nt*64 + lane)*8);
    #pragma unroll
    for (int rt = 0; rt < 2; rt++) {
      short8 af;
      if (kg == 0) {
        af[0]=(short)f2b(np[rt][0]); af[1]=(short)f2b(np[rt][1]); af[2]=(short)f2b(np[rt][2]);
        af[3]=(short)r0[rt][0]; af[4]=(short)r0[rt][1]; af[5]=(short)r0[rt][2];
        af[6]=(short)r0[rt][3]; af[7]=(short)r0[rt][4];
      } else if (kg == 1) {
        af[0]=(short)r0[rt][5]; af[1]=(short)r0[rt][6]; af[2]=(short)r0[rt][7];
        af[3]=(short)r1[rt][0]; af[4]=(short)r1[rt][1]; af[5]=(short)r1[rt][2];
        af[6]=(short)r1[rt][3]; af[7]=(short)r1[rt][4];
      } else if (kg == 2) {
        af[0]=(short)r1[rt][5]; af[1]=(short)r1[rt][6];
        af[2]=0; af[3]=0; af[4]=0; af[5]=0; af[6]=0; af[7]=0;
      } else {
        af[0]=0; af[1]=0; af[2]=0; af[3]=0; af[4]=0; af[5]=0; af[6]=0; af[7]=0;
      }
      #pragma unroll
      for (int nt = 0; nt < 8; nt++)
        acc[rt][nt] = __builtin_amdgcn_mfma_f32_16x16x32_bf16(af, bf[nt], acc[rt][nt], 0, 0, 0);
    }
  }
  #pragma unroll
  for (int rt = 0; rt < 2; rt++)
    #pragma unroll
    for (int nt = 0; nt < 8; nt++)
      #pragma unroll
      for (int g = 0; g < 4; g++)
        T[(rt*16 + kg*4 + g)*TS + nt*16 + cl] = f2b(silu_f(acc[rt][nt][g]));

  // ---- pe2 in two N-halves; fold pos write + o=s2*pos + att partial ----
  float ps[2][4] = {{0,0,0,0},{0,0,0,0}};
  #pragma unroll
  for (int half = 0; half < 2; half++) {
    f32x4 ph[2][4];
    #pragma unroll
    for (int n4 = 0; n4 < 4; n4++) {
      float b = bp2[(half*4 + n4)*16 + cl];
      ph[0][n4] = f32x4{b,b,b,b}; ph[1][n4] = f32x4{b,b,b,b};
    }
    #pragma unroll
    for (int kt = 0; kt < 4; kt++) {
      short8 bf[4];
      #pragma unroll
      for (int n4 = 0; n4 < 4; n4++)
        bf[n4] = *reinterpret_cast<const short8*>(wp + 81920 + ((kt*8 + half*4 + n4)*64 + lane)*8);
      #pragma unroll
      for (int rt = 0; rt < 2; rt++) {
        short8 af = *reinterpret_cast<const short8*>(T + (rt*16 + cl)*TS + kt*32 + kg*8);
        #pragma unroll
        for (int n4 = 0; n4 < 4; n4++)
          ph[rt][n4] = __builtin_amdgcn_mfma_f32_16x16x32_bf16(af, bf[n4], ph[rt][n4], 0, 0, 0);
      }
    }
    #pragma unroll
    for (int rt = 0; rt < 2; rt++)
      #pragma unroll
      for (int n4 = 0; n4 < 4; n4++) {
        int nt = half*4 + n4;
        float wa = watt[nt*16 + cl];
        #pragma unroll
        for (int g = 0; g < 4; g++) {
          float p = ph[rt][n4][g];
          pos_o[(size_t)(e0 + rt*16 + kg*4 + g) * HID + nt*16 + cl] = p;
          float o = accS[rt][nt][g] * p;
          accS[rt][nt][g] = o;
          ps[rt][g] += o * wa;
        }
      }
  }

  // ---- attention + final out ----
  float ba = batt[0];
  #pragma unroll
  for (int rt = 0; rt < 2; rt++)
    #pragma unroll
    for (int g = 0; g < 4; g++) {
      float s = ps[rt][g];
      s += __shfl_xor(s, 1);
      s += __shfl_xor(s, 2);
      s += __shfl_xor(s, 4);
      s += __shfl_xor(s, 8);
      float av = 1.0f / (1.0f + __expf(-(s + ba)));
      #pragma unroll
      for (int nt = 0; nt < 8; nt++)
        out0[(size_t)(e0 + rt*16 + kg*4 + g) * HID + nt*16 + cl] = accS[rt][nt][g] * av;
    }
}

// ---------------- launcher ----------------------------------------------------
extern "C" void kernel_launch(void* const* d_in, const int* in_sizes, int n_in,
                              void* d_out, int out_size, void* d_ws, size_t ws_size,
                              hipStream_t stream) {
  (void)in_sizes; (void)n_in; (void)out_size; (void)ws_size;
  const float* h     = (const float*)d_in[0];
  const float* coord = (const float*)d_in[1];
  const int*   edges = (const int*)d_in[2];
  const float* W_ce1 = (const float*)d_in[3];  const float* b_ce1 = (const float*)d_in[4];
  const float* W_ce2 = (const float*)d_in[5];  const float* b_ce2 = (const float*)d_in[6];
  const float* W_pe1 = (const float*)d_in[7];  const float* b_pe1 = (const float*)d_in[8];
  const float* W_pe2 = (const float*)d_in[9];  const float* b_pe2 = (const float*)d_in[10];
  const float* W_s1  = (const float*)d_in[11]; const float* b_s1  = (const float*)d_in[12];
  const float* W_s2  = (const float*)d_in[13]; const float* b_s2  = (const float*)d_in[14];
  const float* W_att = (const float*)d_in[15]; const float* b_att = (const float*)d_in[16];

  float* out  = (float*)d_out;
  float* chem = out  + (size_t)E_EDGES * HID;
  float* pos  = chem + (size_t)E_EDGES * HID;
  float* cdn  = pos  + (size_t)E_EDGES * HID;

  float* nf    = (float*)d_ws;                                    // [NN*9]
  float* cnt   = nf + NN * 9;                                     // [NN]
  float* nvecs = cnt + NN;                                        // [NN*9]
  unsigned short* wpack = (unsigned short*)(nvecs + NN * 9);      // 102400 bf16
  unsigned short* rad16 = wpack + 102400;                         // [E*16] bf16 (10.24 MB)

  hipMemsetAsync(nf, 0, (size_t)(NN * 10) * sizeof(float), stream);
  prepack_k<<<400, 256, 0, stream>>>(W_ce1, W_ce2, W_s1, W_s2, W_pe2, W_pe1, wpack);
  edge_geom_k<<<E_EDGES / 256, 256, 0, stream>>>(edges, edges + E_EDGES, coord,
                                                 nf, cnt, cdn, rad16);
  node_norm_k<<<(NN + 255) / 256, 256, 0, stream>>>(nf, cnt, nvecs);
  chem_k<<<E_EDGES / 128, 256, 0, stream>>>(edges, edges + E_EDGES, h, wpack,
                                            b_ce1, b_ce2, chem);
  simpos_k<<<E_EDGES / 128, 256, 0, stream>>>(edges, edges + E_EDGES, chem, rad16,
                                              nvecs, wpack, b_s1, b_s2, b_pe1, b_pe2,
                                              W_att, b_att, out, pos);
}

// Round 4
// 467.346 us; speedup vs baseline: 1.1207x; 1.0006x over previous
//
#include <hip/hip_runtime.h>

#define E_EDGES 320000
#define NN 20000
#define HID 128
#define TS 136   // LDS T-tile stride (bf16 elems): 272B == 16 mod 128 -> spread banks

typedef __attribute__((ext_vector_type(8))) short short8;
typedef __attribute__((ext_vector_type(4))) float f32x4;
typedef __attribute__((ext_vector_type(8))) unsigned short us8;

__device__ __forceinline__ unsigned short f2b(float f) {
  unsigned u = __builtin_bit_cast(unsigned, f);
  u += 0x7fffu + ((u >> 16) & 1u);
  return (unsigned short)(u >> 16);
}
__device__ __forceinline__ float silu_f(float x) { return x / (1.0f + __expf(-x)); }

// ---------------- workspace zero-init (replaces pathological hipMemsetAsync) --
__global__ void zero_k(float* __restrict__ p, int n4) {
  int i = blockIdx.x * 256 + threadIdx.x;
  if (i < n4) reinterpret_cast<float4*>(p)[i] = float4{0.0f, 0.0f, 0.0f, 0.0f};
}

// ---------------- weight prepack: f32 [K][128] -> bf16 MFMA-fragment order ---
// dst[((kt*8 + ntg)*64 + lane)*8 + r] = W[kt*32 + (lane>>4)*8 + r][ntg*16 + (lane&15)]
__global__ void prepack_k(const float* __restrict__ Wce1, const float* __restrict__ Wce2,
                          const float* __restrict__ Ws1,  const float* __restrict__ Ws2,
                          const float* __restrict__ Wpe2, const float* __restrict__ Wpe1,
                          unsigned short* __restrict__ dst) {
  int i = blockIdx.x * 256 + threadIdx.x;          // grid covers exactly 102400
  const float* W; int Ksrc, base;
  if (i < 32768)      { W = Wce1; Ksrc = 256; base = 0; }
  else if (i < 49152) { W = Wce2; Ksrc = 128; base = 32768; }
  else if (i < 65536) { W = Ws1;  Ksrc = 128; base = 49152; }
  else if (i < 81920) { W = Ws2;  Ksrc = 128; base = 65536; }
  else if (i < 98304) { W = Wpe2; Ksrc = 128; base = 81920; }
  else                { W = Wpe1; Ksrc = 18;  base = 98304; }
  int j = i - base;
  int r = j & 7, lane = (j >> 3) & 63, ntg = (j >> 9) & 7, kt = j >> 12;
  int sk = kt * 32 + ((lane >> 4) << 3) + r;
  int sn = (ntg << 4) + (lane & 15);
  float v = (sk < Ksrc) ? W[sk * HID + sn] : 0.0f;
  dst[i] = f2b(v);
}

// ---------------- per-edge geometry + segment-sum atomics + radial table -----
__global__ void edge_geom_k(const int* __restrict__ erow, const int* __restrict__ ecol,
                            const float* __restrict__ coord,
                            float* __restrict__ nf, float* __restrict__ cnt,
                            float* __restrict__ cdn, unsigned short* __restrict__ rad16) {
  int i = blockIdx.x * 256 + threadIdx.x;
  if (i >= E_EDGES) return;
  int r = erow[i], c = ecol[i];
  float dx = coord[r*3+0] - coord[c*3+0];
  float dy = coord[r*3+1] - coord[c*3+1];
  float dz = coord[r*3+2] - coord[c*3+2];
  float r2 = dx*dx + dy*dy + dz*dz;
  float dn = sqrtf(r2);
  float invn = 1.0f / (dn + 1e-8f);
  cdn[i*3+0] = dx*invn; cdn[i*3+1] = dy*invn; cdn[i*3+2] = dz*invn;

  unsigned short rv[16];
  float t = 1.0f;
  #pragma unroll
  for (int s = 0; s < 15; s++) { rv[s] = f2b(__expf(r2 * (-0.5f / t))); t *= 2.25f; }
  rv[15] = 0;
  us8 lo, hi;
  #pragma unroll
  for (int k = 0; k < 8; k++) { lo[k] = rv[k]; hi[k] = rv[8+k]; }
  *reinterpret_cast<us8*>(rad16 + (size_t)i*16)     = lo;
  *reinterpret_cast<us8*>(rad16 + (size_t)i*16 + 8) = hi;

  float inv = 1.0f / dn;
  float w3 = inv*inv*inv, w4 = w3*inv, w5 = w4*inv;
  float* p = nf + r*9;
  atomicAdd(p+0, w3*dx); atomicAdd(p+1, w3*dy); atomicAdd(p+2, w3*dz);
  atomicAdd(p+3, w4*dx); atomicAdd(p+4, w4*dy); atomicAdd(p+5, w4*dz);
  atomicAdd(p+6, w5*dx); atomicAdd(p+7, w5*dy); atomicAdd(p+8, w5*dz);
  atomicAdd(cnt + r, 1.0f);
}

// ---------------- per-node normalize -----------------------------------------
__global__ void node_norm_k(const float* __restrict__ nf, const float* __restrict__ cnt,
                            float* __restrict__ nvecs) {
  int n = blockIdx.x * 256 + threadIdx.x;
  if (n >= NN) return;
  float cinv = 1.0f / fmaxf(cnt[n], 1.0f);
  #pragma unroll
  for (int a = 0; a < 3; a++) {
    float x = nf[n*9+a*3+0]*cinv, y = nf[n*9+a*3+1]*cinv, z = nf[n*9+a*3+2]*cinv;
    float nm = sqrtf(x*x + y*y + z*z);
    float s = 1.0f / (nm + 1e-8f);
    nvecs[n*9+a*3+0] = x*s; nvecs[n*9+a*3+1] = y*s; nvecs[n*9+a*3+2] = z*s;
  }
}

// ---------------- chem kernel: ce1 + ce2, 32 edges per wave -------------------
__global__ __launch_bounds__(256) void chem_k(
    const int* __restrict__ erow, const int* __restrict__ ecol,
    const float* __restrict__ h, const unsigned short* __restrict__ wp,
    const float* __restrict__ b1, const float* __restrict__ b2,
    float* __restrict__ chem_o) {
  __shared__ unsigned short sT[4][32 * TS];
  const int tid = threadIdx.x, lane = tid & 63, wv = tid >> 6;
  const int cl = lane & 15, kg = lane >> 4;
  const int e0 = (blockIdx.x * 4 + wv) * 32;
  unsigned short* T = sT[wv];

  int er[2], ec[2];
  er[0] = erow[e0 + cl];      ec[0] = ecol[e0 + cl];
  er[1] = erow[e0 + 16 + cl]; ec[1] = ecol[e0 + 16 + cl];

  f32x4 acc[2][8];
  #pragma unroll
  for (int nt = 0; nt < 8; nt++) {
    float b = b1[nt*16 + cl];
    acc[0][nt] = f32x4{b,b,b,b}; acc[1][nt] = f32x4{b,b,b,b};
  }
  #pragma unroll
  for (int kt = 0; kt < 8; kt++) {
    short8 bf[8];
    #pragma unroll
    for (int nt = 0; nt < 8; nt++)
      bf[nt] = *reinterpret_cast<const short8*>(wp + ((kt*8 + nt)*64 + lane)*8);
    #pragma unroll
    for (int rt = 0; rt < 2; rt++) {
      int node = (kt < 4) ? er[rt] : ec[rt];
      const float* hp = h + (size_t)node * HID + (kt & 3)*32 + kg*8;
      float4 v0 = *reinterpret_cast<const float4*>(hp);
      float4 v1 = *reinterpret_cast<const float4*>(hp + 4);
      short8 af;
      af[0]=(short)f2b(v0.x); af[1]=(short)f2b(v0.y); af[2]=(short)f2b(v0.z); af[3]=(short)f2b(v0.w);
      af[4]=(short)f2b(v1.x); af[5]=(short)f2b(v1.y); af[6]=(short)f2b(v1.z); af[7]=(short)f2b(v1.w);
      #pragma unroll
      for (int nt = 0; nt < 8; nt++)
        acc[rt][nt] = __builtin_amdgcn_mfma_f32_16x16x32_bf16(af, bf[nt], acc[rt][nt], 0, 0, 0);
    }
  }
  #pragma unroll
  for (int rt = 0; rt < 2; rt++)
    #pragma unroll
    for (int nt = 0; nt < 8; nt++)
      #pragma unroll
      for (int g = 0; g < 4; g++)
        T[(rt*16 + kg*4 + g)*TS + nt*16 + cl] = f2b(silu_f(acc[rt][nt][g]));

  // ce2 (wave-private T: DS ops are program-ordered, no barrier)
  #pragma unroll
  for (int nt = 0; nt < 8; nt++) {
    float b = b2[nt*16 + cl];
    acc[0][nt] = f32x4{b,b,b,b}; acc[1][nt] = f32x4{b,b,b,b};
  }
  #pragma unroll
  for (int kt = 0; kt < 4; kt++) {
    short8 bf[8];
    #pragma unroll
    for (int nt = 0; nt < 8; nt++)
      bf[nt] = *reinterpret_cast<const short8*>(wp + 32768 + ((kt*8 + nt)*64 + lane)*8);
    #pragma unroll
    for (int rt = 0; rt < 2; rt++) {
      short8 af = *reinterpret_cast<const short8*>(T + (rt*16 + cl)*TS + kt*32 + kg*8);
      #pragma unroll
      for (int nt = 0; nt < 8; nt++)
        acc[rt][nt] = __builtin_amdgcn_mfma_f32_16x16x32_bf16(af, bf[nt], acc[rt][nt], 0, 0, 0);
    }
  }
  #pragma unroll
  for (int rt = 0; rt < 2; rt++)
    #pragma unroll
    for (int nt = 0; nt < 8; nt++)
      #pragma unroll
      for (int g = 0; g < 4; g++)
        chem_o[(size_t)(e0 + rt*16 + kg*4 + g) * HID + nt*16 + cl] = acc[rt][nt][g];
}

// ---------------- sim+pos kernel: s1+s2+pe1+pe2+att, 32 edges per wave --------
__global__ __launch_bounds__(256) void simpos_k(
    const int* __restrict__ erow, const int* __restrict__ ecol,
    const float* __restrict__ chem_f, const unsigned short* __restrict__ rad16,
    const float* __restrict__ nvecs, const unsigned short* __restrict__ wp,
    const float* __restrict__ bs1, const float* __restrict__ bs2,
    const float* __restrict__ bp1, const float* __restrict__ bp2,
    const float* __restrict__ watt, const float* __restrict__ batt,
    float* __restrict__ out0, float* __restrict__ pos_o) {
  __shared__ unsigned short sT[4][32 * TS];
  const int tid = threadIdx.x, lane = tid & 63, wv = tid >> 6;
  const int cl = lane & 15, kg = lane >> 4;
  const int e0 = (blockIdx.x * 4 + wv) * 32;
  unsigned short* T = sT[wv];

  // ---- s1: A = chem (f32, streamed) ----
  f32x4 acc[2][8];
  #pragma unroll
  for (int nt = 0; nt < 8; nt++) {
    float b = bs1[nt*16 + cl];
    acc[0][nt] = f32x4{b,b,b,b}; acc[1][nt] = f32x4{b,b,b,b};
  }
  #pragma unroll
  for (int kt = 0; kt < 4; kt++) {
    short8 bf[8];
    #pragma unroll
    for (int nt = 0; nt < 8; nt++)
      bf[nt] = *reinterpret_cast<const short8*>(wp + 49152 + ((kt*8 + nt)*64 + lane)*8);
    #pragma unroll
    for (int rt = 0; rt < 2; rt++) {
      const float* cp = chem_f + (size_t)(e0 + rt*16 + cl) * HID + kt*32 + kg*8;
      float4 v0 = *reinterpret_cast<const float4*>(cp);
      float4 v1 = *reinterpret_cast<const float4*>(cp + 4);
      short8 af;
      af[0]=(short)f2b(v0.x); af[1]=(short)f2b(v0.y); af[2]=(short)f2b(v0.z); af[3]=(short)f2b(v0.w);
      af[4]=(short)f2b(v1.x); af[5]=(short)f2b(v1.y); af[6]=(short)f2b(v1.z); af[7]=(short)f2b(v1.w);
      #pragma unroll
      for (int nt = 0; nt < 8; nt++)
        acc[rt][nt] = __builtin_amdgcn_mfma_f32_16x16x32_bf16(af, bf[nt], acc[rt][nt], 0, 0, 0);
    }
  }
  #pragma unroll
  for (int rt = 0; rt < 2; rt++)
    #pragma unroll
    for (int nt = 0; nt < 8; nt++)
      #pragma unroll
      for (int g = 0; g < 4; g++)
        T[(rt*16 + kg*4 + g)*TS + nt*16 + cl] = f2b(silu_f(acc[rt][nt][g]));

  // ---- s2 -> accS (held) ----
  f32x4 accS[2][8];
  #pragma unroll
  for (int nt = 0; nt < 8; nt++) {
    float b = bs2[nt*16 + cl];
    accS[0][nt] = f32x4{b,b,b,b}; accS[1][nt] = f32x4{b,b,b,b};
  }
  #pragma unroll
  for (int kt = 0; kt < 4; kt++) {
    short8 bf[8];
    #pragma unroll
    for (int nt = 0; nt < 8; nt++)
      bf[nt] = *reinterpret_cast<const short8*>(wp + 65536 + ((kt*8 + nt)*64 + lane)*8);
    #pragma unroll
    for (int rt = 0; rt < 2; rt++) {
      short8 af = *reinterpret_cast<const short8*>(T + (rt*16 + cl)*TS + kt*32 + kg*8);
      #pragma unroll
      for (int nt = 0; nt < 8; nt++)
        accS[rt][nt] = __builtin_amdgcn_mfma_f32_16x16x32_bf16(af, bf[nt], accS[rt][nt], 0, 0, 0);
    }
  }

  // ---- pe1: pin = [nprod(3) | radial(15) | pad] assembled in-register ----
  us8 r0[2], r1[2];
  #pragma unroll
  for (int rt = 0; rt < 2; rt++) {
    r0[rt] = *reinterpret_cast<const us8*>(rad16 + (size_t)(e0 + rt*16 + cl)*16);
    r1[rt] = *reinterpret_cast<const us8*>(rad16 + (size_t)(e0 + rt*16 + cl)*16 + 8);
  }
  float np[2][3];
  if (kg == 0) {
    #pragma unroll
    for (int rt = 0; rt < 2; rt++) {
      int er_ = erow[e0 + rt*16 + cl], ec_ = ecol[e0 + rt*16 + cl];
      #pragma unroll
      for (int a = 0; a < 3; a++)
        np[rt][a] = nvecs[er_*9+a*3+0]*nvecs[ec_*9+a*3+0]
                  + nvecs[er_*9+a*3+1]*nvecs[ec_*9+a*3+1]
                  + nvecs[er_*9+a*3+2]*nvecs[ec_*9+a*3+2];
    }
  }
  #pragma unroll
  for (int nt = 0; nt < 8; nt++) {
    float b = bp1[nt*16 + cl];
    acc[0][nt] = f32x4{b,b,b,b}; acc[1][nt] = f32x4{b,b,b,b};
  }
  {
    short8 bf[8];
    #pragma unroll
    for (int nt = 0; nt < 8; nt++)
      bf[nt] = *reinterpret_cast<const short8*>(wp + 98304 + (nt*64 + lane)*8);
    #pragma unroll
    for (int rt = 0; rt < 2; rt++) {
      short8 af;
      if (kg == 0) {
        af[0]=(short)f2b(np[rt][0]); af[1]=(short)f2b(np[rt][1]); af[2]=(short)f2b(np[rt][2]);
        af[3]=(short)r0[rt][0]; af[4]=(short)r0[rt][1]; af[5]=(short)r0[rt][2];
        af[6]=(short)r0[rt][3]; af[7]=(short)r0[rt][4];
      } else if (kg == 1) {
        af[0]=(short)r0[rt][5]; af[1]=(short)r0[rt][6]; af[2]=(short)r0[rt][7];
        af[3]=(short)r1[rt][0]; af[4]=(short)r1[rt][1]; af[5]=(short)r1[rt][2];
        af[6]=(short)r1[rt][3]; af[7]=(short)r1[rt][4];
      } else if (kg == 2) {
        af[0]=(short)r1[rt][5]; af[1]=(short)r1[rt][6];
        af[2]=0; af[3]=0; af[4]=0; af[5]=0; af[6]=0; af[7]=0;
      } else {
        af[0]=0; af[1]=0; af[2]=0; af[3]=0; af[4]=0; af[5]=0; af[6]=0; af[7]=0;
      }
      #pragma unroll
      for (int nt = 0; nt < 8; nt++)
        acc[rt][nt] = __builtin_amdgcn_mfma_f32_16x16x32_bf16(af, bf[nt], acc[rt][nt], 0, 0, 0);
    }
  }
  #pragma unroll
  for (int rt = 0; rt < 2; rt++)
    #pragma unroll
    for (int nt = 0; nt < 8; nt++)
      #pragma unroll
      for (int g = 0; g < 4; g++)
        T[(rt*16 + kg*4 + g)*TS + nt*16 + cl] = f2b(silu_f(acc[rt][nt][g]));

  // ---- pe2 in two N-halves; fold pos write + o=s2*pos + att partial ----
  float ps[2][4] = {{0,0,0,0},{0,0,0,0}};
  #pragma unroll
  for (int half = 0; half < 2; half++) {
    f32x4 ph[2][4];
    #pragma unroll
    for (int n4 = 0; n4 < 4; n4++) {
      float b = bp2[(half*4 + n4)*16 + cl];
      ph[0][n4] = f32x4{b,b,b,b}; ph[1][n4] = f32x4{b,b,b,b};
    }
    #pragma unroll
    for (int kt = 0; kt < 4; kt++) {
      short8 bf[4];
      #pragma unroll
      for (int n4 = 0; n4 < 4; n4++)
        bf[n4] = *reinterpret_cast<const short8*>(wp + 81920 + ((kt*8 + half*4 + n4)*64 + lane)*8);
      #pragma unroll
      for (int rt = 0; rt < 2; rt++) {
        short8 af = *reinterpret_cast<const short8*>(T + (rt*16 + cl)*TS + kt*32 + kg*8);
        #pragma unroll
        for (int n4 = 0; n4 < 4; n4++)
          ph[rt][n4] = __builtin_amdgcn_mfma_f32_16x16x32_bf16(af, bf[n4], ph[rt][n4], 0, 0, 0);
      }
    }
    #pragma unroll
    for (int rt = 0; rt < 2; rt++)
      #pragma unroll
      for (int n4 = 0; n4 < 4; n4++) {
        int nt = half*4 + n4;
        float wa = watt[nt*16 + cl];
        #pragma unroll
        for (int g = 0; g < 4; g++) {
          float p = ph[rt][n4][g];
          pos_o[(size_t)(e0 + rt*16 + kg*4 + g) * HID + nt*16 + cl] = p;
          float o = accS[rt][nt][g] * p;
          accS[rt][nt][g] = o;
          ps[rt][g] += o * wa;
        }
      }
  }

  // ---- attention + final out ----
  float ba = batt[0];
  #pragma unroll
  for (int rt = 0; rt < 2; rt++)
    #pragma unroll
    for (int g = 0; g < 4; g++) {
      float s = ps[rt][g];
      s += __shfl_xor(s, 1);
      s += __shfl_xor(s, 2);
      s += __shfl_xor(s, 4);
      s += __shfl_xor(s, 8);
      float av = 1.0f / (1.0f + __expf(-(s + ba)));
      #pragma unroll
      for (int nt = 0; nt < 8; nt++)
        out0[(size_t)(e0 + rt*16 + kg*4 + g) * HID + nt*16 + cl] = accS[rt][nt][g] * av;
    }
}

// ---------------- launcher ----------------------------------------------------
extern "C" void kernel_launch(void* const* d_in, const int* in_sizes, int n_in,
                              void* d_out, int out_size, void* d_ws, size_t ws_size,
                              hipStream_t stream) {
  (void)in_sizes; (void)n_in; (void)out_size; (void)ws_size;
  const float* h     = (const float*)d_in[0];
  const float* coord = (const float*)d_in[1];
  const int*   edges = (const int*)d_in[2];
  const float* W_ce1 = (const float*)d_in[3];  const float* b_ce1 = (const float*)d_in[4];
  const float* W_ce2 = (const float*)d_in[5];  const float* b_ce2 = (const float*)d_in[6];
  const float* W_pe1 = (const float*)d_in[7];  const float* b_pe1 = (const float*)d_in[8];
  const float* W_pe2 = (const float*)d_in[9];  const float* b_pe2 = (const float*)d_in[10];
  const float* W_s1  = (const float*)d_in[11]; const float* b_s1  = (const float*)d_in[12];
  const float* W_s2  = (const float*)d_in[13]; const float* b_s2  = (const float*)d_in[14];
  const float* W_att = (const float*)d_in[15]; const float* b_att = (const float*)d_in[16];

  float* out  = (float*)d_out;
  float* chem = out  + (size_t)E_EDGES * HID;
  float* pos  = chem + (size_t)E_EDGES * HID;
  float* cdn  = pos  + (size_t)E_EDGES * HID;

  float* nf    = (float*)d_ws;                                    // [NN*9]
  float* cnt   = nf + NN * 9;                                     // [NN]
  float* nvecs = cnt + NN;                                        // [NN*9]
  unsigned short* wpack = (unsigned short*)(nvecs + NN * 9);      // 102400 bf16
  unsigned short* rad16 = wpack + 102400;                         // [E*16] bf16 (10.24 MB)

  zero_k<<<(NN * 10 / 4 + 255) / 256, 256, 0, stream>>>(nf, NN * 10 / 4);
  prepack_k<<<400, 256, 0, stream>>>(W_ce1, W_ce2, W_s1, W_s2, W_pe2, W_pe1, wpack);
  edge_geom_k<<<E_EDGES / 256, 256, 0, stream>>>(edges, edges + E_EDGES, coord,
                                                 nf, cnt, cdn, rad16);
  node_norm_k<<<(NN + 255) / 256, 256, 0, stream>>>(nf, cnt, nvecs);
  chem_k<<<E_EDGES / 128, 256, 0, stream>>>(edges, edges + E_EDGES, h, wpack,
                                            b_ce1, b_ce2, chem);
  simpos_k<<<E_EDGES / 128, 256, 0, stream>>>(edges, edges + E_EDGES, chem, rad16,
                                              nvecs, wpack, b_s1, b_s2, b_pe1, b_pe2,
                                              W_att, b_att, out, pos);
}

// Round 5
// 455.471 us; speedup vs baseline: 1.1499x; 1.0261x over previous
//
#include <hip/hip_runtime.h>

#define E_EDGES 320000
#define NN 20000
#define HID 128
#define TS 136   // LDS T-tile stride (bf16 elems): 272B == 16 mod 128 -> spread banks

typedef __attribute__((ext_vector_type(8))) short short8;
typedef __attribute__((ext_vector_type(4))) float f32x4;
typedef __attribute__((ext_vector_type(8))) unsigned short us8;

__device__ __forceinline__ unsigned short f2b(float f) {
  unsigned u = __builtin_bit_cast(unsigned, f);
  u += 0x7fffu + ((u >> 16) & 1u);
  return (unsigned short)(u >> 16);
}
__device__ __forceinline__ float silu_f(float x) { return x / (1.0f + __expf(-x)); }

// ---------------- workspace zero-init ----------------------------------------
__global__ void zero_k(float* __restrict__ p, int n4) {
  int i = blockIdx.x * 256 + threadIdx.x;
  if (i < n4) reinterpret_cast<float4*>(p)[i] = float4{0.0f, 0.0f, 0.0f, 0.0f};
}

// ---------------- weight prepack: f32 [K][128] -> bf16 MFMA-fragment order ---
// dst[((kt*8 + ntg)*64 + lane)*8 + r] = W[kt*32 + (lane>>4)*8 + r][ntg*16 + (lane&15)]
__global__ void prepack_k(const float* __restrict__ Wce1, const float* __restrict__ Wce2,
                          const float* __restrict__ Ws1,  const float* __restrict__ Ws2,
                          const float* __restrict__ Wpe2, const float* __restrict__ Wpe1,
                          unsigned short* __restrict__ dst) {
  int i = blockIdx.x * 256 + threadIdx.x;          // grid covers exactly 102400
  const float* W; int Ksrc, base;
  if (i < 32768)      { W = Wce1; Ksrc = 256; base = 0; }
  else if (i < 49152) { W = Wce2; Ksrc = 128; base = 32768; }
  else if (i < 65536) { W = Ws1;  Ksrc = 128; base = 49152; }
  else if (i < 81920) { W = Ws2;  Ksrc = 128; base = 65536; }
  else if (i < 98304) { W = Wpe2; Ksrc = 128; base = 81920; }
  else                { W = Wpe1; Ksrc = 18;  base = 98304; }
  int j = i - base;
  int r = j & 7, lane = (j >> 3) & 63, ntg = (j >> 9) & 7, kt = j >> 12;
  int sk = kt * 32 + ((lane >> 4) << 3) + r;
  int sn = (ntg << 4) + (lane & 15);
  float v = (sk < Ksrc) ? W[sk * HID + sn] : 0.0f;
  dst[i] = f2b(v);
}

// ---------------- per-edge geometry + segment-sum atomics + radial table -----
__global__ void edge_geom_k(const int* __restrict__ erow, const int* __restrict__ ecol,
                            const float* __restrict__ coord,
                            float* __restrict__ nf,
                            float* __restrict__ cdn, unsigned short* __restrict__ rad16) {
  int i = blockIdx.x * 256 + threadIdx.x;
  if (i >= E_EDGES) return;
  int r = erow[i], c = ecol[i];
  float dx = coord[r*3+0] - coord[c*3+0];
  float dy = coord[r*3+1] - coord[c*3+1];
  float dz = coord[r*3+2] - coord[c*3+2];
  float r2 = dx*dx + dy*dy + dz*dz;
  float dn = sqrtf(r2);
  float invn = 1.0f / (dn + 1e-8f);
  cdn[i*3+0] = dx*invn; cdn[i*3+1] = dy*invn; cdn[i*3+2] = dz*invn;

  unsigned short rv[16];
  float t = 1.0f;
  #pragma unroll
  for (int s = 0; s < 15; s++) { rv[s] = f2b(__expf(r2 * (-0.5f / t))); t *= 2.25f; }
  rv[15] = 0;
  us8 lo, hi;
  #pragma unroll
  for (int k = 0; k < 8; k++) { lo[k] = rv[k]; hi[k] = rv[8+k]; }
  *reinterpret_cast<us8*>(rad16 + (size_t)i*16)     = lo;
  *reinterpret_cast<us8*>(rad16 + (size_t)i*16 + 8) = hi;

  float inv = 1.0f / dn;
  float w3 = inv*inv*inv, w4 = w3*inv, w5 = w4*inv;
  float* p = nf + r*9;
  atomicAdd(p+0, w3*dx); atomicAdd(p+1, w3*dy); atomicAdd(p+2, w3*dz);
  atomicAdd(p+3, w4*dx); atomicAdd(p+4, w4*dy); atomicAdd(p+5, w4*dz);
  atomicAdd(p+6, w5*dx); atomicAdd(p+7, w5*dy); atomicAdd(p+8, w5*dz);
}

// ---------------- per-node normalize ------------------------------------------
// denom cancels under normalization: (s/d)/(|s/d|+eps) = s/(|s|+d*eps) ~= s/(|s|+eps)
// (rel diff ~(d-1)*1e-8/|s| ~ 1e-6, far below tolerance)
__global__ void node_norm_k(const float* __restrict__ nf, float* __restrict__ nvecs) {
  int n = blockIdx.x * 256 + threadIdx.x;
  if (n >= NN) return;
  #pragma unroll
  for (int a = 0; a < 3; a++) {
    float x = nf[n*9+a*3+0], y = nf[n*9+a*3+1], z = nf[n*9+a*3+2];
    float nm = sqrtf(x*x + y*y + z*z);
    float s = 1.0f / (nm + 1e-8f);
    nvecs[n*9+a*3+0] = x*s; nvecs[n*9+a*3+1] = y*s; nvecs[n*9+a*3+2] = z*s;
  }
}

// ---------------- node-level ce1 halves: Htop = h@Wt + b1, Hbot = h@Wb --------
__global__ __launch_bounds__(256) void node_mlp_k(
    const float* __restrict__ h, const unsigned short* __restrict__ wp,
    const float* __restrict__ b1,
    float* __restrict__ Htop, float* __restrict__ Hbot) {
  const int tid = threadIdx.x, lane = tid & 63, wv = tid >> 6;
  const int cl = lane & 15, kg = lane >> 4;
  const int n0 = (blockIdx.x * 4 + wv) * 32;   // this wave's 32 nodes
  if (n0 >= NN) return;

  #pragma unroll
  for (int half = 0; half < 2; half++) {       // 0: Wt rows 0-127, 1: Wb rows 128-255
    f32x4 acc[2][8];
    #pragma unroll
    for (int nt = 0; nt < 8; nt++) {
      float b = half ? 0.0f : b1[nt*16 + cl];
      acc[0][nt] = f32x4{b,b,b,b}; acc[1][nt] = f32x4{b,b,b,b};
    }
    #pragma unroll
    for (int k4 = 0; k4 < 4; k4++) {
      int kt = half*4 + k4;
      short8 bf[8];
      #pragma unroll
      for (int nt = 0; nt < 8; nt++)
        bf[nt] = *reinterpret_cast<const short8*>(wp + ((kt*8 + nt)*64 + lane)*8);
      #pragma unroll
      for (int rt = 0; rt < 2; rt++) {
        int node = n0 + rt*16 + cl;
        if (node >= NN) node = 0;
        const float* hp = h + (size_t)node * HID + k4*32 + kg*8;
        float4 v0 = *reinterpret_cast<const float4*>(hp);
        float4 v1 = *reinterpret_cast<const float4*>(hp + 4);
        short8 af;
        af[0]=(short)f2b(v0.x); af[1]=(short)f2b(v0.y); af[2]=(short)f2b(v0.z); af[3]=(short)f2b(v0.w);
        af[4]=(short)f2b(v1.x); af[5]=(short)f2b(v1.y); af[6]=(short)f2b(v1.z); af[7]=(short)f2b(v1.w);
        #pragma unroll
        for (int nt = 0; nt < 8; nt++)
          acc[rt][nt] = __builtin_amdgcn_mfma_f32_16x16x32_bf16(af, bf[nt], acc[rt][nt], 0, 0, 0);
      }
    }
    float* dst = half ? Hbot : Htop;
    #pragma unroll
    for (int rt = 0; rt < 2; rt++)
      #pragma unroll
      for (int nt = 0; nt < 8; nt++)
        #pragma unroll
        for (int g = 0; g < 4; g++) {
          int node = n0 + rt*16 + kg*4 + g;
          if (node < NN) dst[(size_t)node * HID + nt*16 + cl] = acc[rt][nt][g];
        }
  }
}

// ---------------- chem kernel: gather(Htop+Hbot)+silu, then ce2 ---------------
__global__ __launch_bounds__(256) void chem_k(
    const int* __restrict__ erow, const int* __restrict__ ecol,
    const float* __restrict__ Htop, const float* __restrict__ Hbot,
    const unsigned short* __restrict__ wp, const float* __restrict__ b2,
    float* __restrict__ chem_o) {
  __shared__ unsigned short sT[4][32 * TS];
  const int tid = threadIdx.x, lane = tid & 63, wv = tid >> 6;
  const int cl = lane & 15, kg = lane >> 4;
  const int e0 = (blockIdx.x * 4 + wv) * 32;
  unsigned short* T = sT[wv];

  // ---- t1 = silu(Htop[row] + Hbot[col]) -> T (each lane: 1 edge-half, 64 f32)
  {
    int edge = lane & 31, half = lane >> 5;
    int er_ = erow[e0 + edge], ec_ = ecol[e0 + edge];
    const float4* tp = reinterpret_cast<const float4*>(Htop + (size_t)er_ * HID + half*64);
    const float4* bp = reinterpret_cast<const float4*>(Hbot + (size_t)ec_ * HID + half*64);
    #pragma unroll
    for (int k8 = 0; k8 < 8; k8++) {
      float4 a0 = tp[k8*2],     b0 = bp[k8*2];
      float4 a1 = tp[k8*2 + 1], b1v = bp[k8*2 + 1];
      us8 w;
      w[0] = f2b(silu_f(a0.x + b0.x)); w[1] = f2b(silu_f(a0.y + b0.y));
      w[2] = f2b(silu_f(a0.z + b0.z)); w[3] = f2b(silu_f(a0.w + b0.w));
      w[4] = f2b(silu_f(a1.x + b1v.x)); w[5] = f2b(silu_f(a1.y + b1v.y));
      w[6] = f2b(silu_f(a1.z + b1v.z)); w[7] = f2b(silu_f(a1.w + b1v.w));
      *reinterpret_cast<us8*>(T + edge*TS + half*64 + k8*8) = w;
    }
  }

  // ---- ce2: chem = T @ Wce2 + b2 (wave-private T, no barrier needed) ----
  f32x4 acc[2][8];
  #pragma unroll
  for (int nt = 0; nt < 8; nt++) {
    float b = b2[nt*16 + cl];
    acc[0][nt] = f32x4{b,b,b,b}; acc[1][nt] = f32x4{b,b,b,b};
  }
  #pragma unroll
  for (int kt = 0; kt < 4; kt++) {
    short8 bf[8];
    #pragma unroll
    for (int nt = 0; nt < 8; nt++)
      bf[nt] = *reinterpret_cast<const short8*>(wp + 32768 + ((kt*8 + nt)*64 + lane)*8);
    #pragma unroll
    for (int rt = 0; rt < 2; rt++) {
      short8 af = *reinterpret_cast<const short8*>(T + (rt*16 + cl)*TS + kt*32 + kg*8);
      #pragma unroll
      for (int nt = 0; nt < 8; nt++)
        acc[rt][nt] = __builtin_amdgcn_mfma_f32_16x16x32_bf16(af, bf[nt], acc[rt][nt], 0, 0, 0);
    }
  }
  #pragma unroll
  for (int rt = 0; rt < 2; rt++)
    #pragma unroll
    for (int nt = 0; nt < 8; nt++)
      #pragma unroll
      for (int g = 0; g < 4; g++)
        chem_o[(size_t)(e0 + rt*16 + kg*4 + g) * HID + nt*16 + cl] = acc[rt][nt][g];
}

// ---------------- sim+pos kernel: s1+s2+pe1+pe2+att, 32 edges per wave --------
__global__ __launch_bounds__(256) void simpos_k(
    const int* __restrict__ erow, const int* __restrict__ ecol,
    const float* __restrict__ chem_f, const unsigned short* __restrict__ rad16,
    const float* __restrict__ nvecs, const unsigned short* __restrict__ wp,
    const float* __restrict__ bs1, const float* __restrict__ bs2,
    const float* __restrict__ bp1, const float* __restrict__ bp2,
    const float* __restrict__ watt, const float* __restrict__ batt,
    float* __restrict__ out0, float* __restrict__ pos_o) {
  __shared__ unsigned short sT[4][32 * TS];
  const int tid = threadIdx.x, lane = tid & 63, wv = tid >> 6;
  const int cl = lane & 15, kg = lane >> 4;
  const int e0 = (blockIdx.x * 4 + wv) * 32;
  unsigned short* T = sT[wv];

  // ---- s1: A = chem (f32, streamed) ----
  f32x4 acc[2][8];
  #pragma unroll
  for (int nt = 0; nt < 8; nt++) {
    float b = bs1[nt*16 + cl];
    acc[0][nt] = f32x4{b,b,b,b}; acc[1][nt] = f32x4{b,b,b,b};
  }
  #pragma unroll
  for (int kt = 0; kt < 4; kt++) {
    short8 bf[8];
    #pragma unroll
    for (int nt = 0; nt < 8; nt++)
      bf[nt] = *reinterpret_cast<const short8*>(wp + 49152 + ((kt*8 + nt)*64 + lane)*8);
    #pragma unroll
    for (int rt = 0; rt < 2; rt++) {
      const float* cp = chem_f + (size_t)(e0 + rt*16 + cl) * HID + kt*32 + kg*8;
      float4 v0 = *reinterpret_cast<const float4*>(cp);
      float4 v1 = *reinterpret_cast<const float4*>(cp + 4);
      short8 af;
      af[0]=(short)f2b(v0.x); af[1]=(short)f2b(v0.y); af[2]=(short)f2b(v0.z); af[3]=(short)f2b(v0.w);
      af[4]=(short)f2b(v1.x); af[5]=(short)f2b(v1.y); af[6]=(short)f2b(v1.z); af[7]=(short)f2b(v1.w);
      #pragma unroll
      for (int nt = 0; nt < 8; nt++)
        acc[rt][nt] = __builtin_amdgcn_mfma_f32_16x16x32_bf16(af, bf[nt], acc[rt][nt], 0, 0, 0);
    }
  }
  #pragma unroll
  for (int rt = 0; rt < 2; rt++)
    #pragma unroll
    for (int nt = 0; nt < 8; nt++)
      #pragma unroll
      for (int g = 0; g < 4; g++)
        T[(rt*16 + kg*4 + g)*TS + nt*16 + cl] = f2b(silu_f(acc[rt][nt][g]));

  // ---- s2 -> accS (held) ----
  f32x4 accS[2][8];
  #pragma unroll
  for (int nt = 0; nt < 8; nt++) {
    float b = bs2[nt*16 + cl];
    accS[0][nt] = f32x4{b,b,b,b}; accS[1][nt] = f32x4{b,b,b,b};
  }
  #pragma unroll
  for (int kt = 0; kt < 4; kt++) {
    short8 bf[8];
    #pragma unroll
    for (int nt = 0; nt < 8; nt++)
      bf[nt] = *reinterpret_cast<const short8*>(wp + 65536 + ((kt*8 + nt)*64 + lane)*8);
    #pragma unroll
    for (int rt = 0; rt < 2; rt++) {
      short8 af = *reinterpret_cast<const short8*>(T + (rt*16 + cl)*TS + kt*32 + kg*8);
      #pragma unroll
      for (int nt = 0; nt < 8; nt++)
        accS[rt][nt] = __builtin_amdgcn_mfma_f32_16x16x32_bf16(af, bf[nt], accS[rt][nt], 0, 0, 0);
    }
  }

  // ---- pe1: pin = [nprod(3) | radial(15) | pad] assembled in-register ----
  us8 r0[2], r1[2];
  #pragma unroll
  for (int rt = 0; rt < 2; rt++) {
    r0[rt] = *reinterpret_cast<const us8*>(rad16 + (size_t)(e0 + rt*16 + cl)*16);
    r1[rt] = *reinterpret_cast<const us8*>(rad16 + (size_t)(e0 + rt*16 + cl)*16 + 8);
  }
  float np[2][3];
  if (kg == 0) {
    #pragma unroll
    for (int rt = 0; rt < 2; rt++) {
      int er_ = erow[e0 + rt*16 + cl], ec_ = ecol[e0 + rt*16 + cl];
      #pragma unroll
      for (int a = 0; a < 3; a++)
        np[rt][a] = nvecs[er_*9+a*3+0]*nvecs[ec_*9+a*3+0]
                  + nvecs[er_*9+a*3+1]*nvecs[ec_*9+a*3+1]
                  + nvecs[er_*9+a*3+2]*nvecs[ec_*9+a*3+2];
    }
  }
  #pragma unroll
  for (int nt = 0; nt < 8; nt++) {
    float b = bp1[nt*16 + cl];
    acc[0][nt] = f32x4{b,b,b,b}; acc[1][nt] = f32x4{b,b,b,b};
  }
  {
    short8 bf[8];
    #pragma unroll
    for (int nt = 0; nt < 8; nt++)
      bf[nt] = *reinterpret_cast<const short8*>(wp + 98304 + (nt*64 + lane)*8);
    #pragma unroll
    for (int rt = 0; rt < 2; rt++) {
      short8 af;
      if (kg == 0) {
        af[0]=(short)f2b(np[rt][0]); af[1]=(short)f2b(np[rt][1]); af[2]=(short)f2b(np[rt][2]);
        af[3]=(short)r0[rt][0]; af[4]=(short)r0[rt][1]; af[5]=(short)r0[rt][2];
        af[6]=(short)r0[rt][3]; af[7]=(short)r0[rt][4];
      } else if (kg == 1) {
        af[0]=(short)r0[rt][5]; af[1]=(short)r0[rt][6]; af[2]=(short)r0[rt][7];
        af[3]=(short)r1[rt][0]; af[4]=(short)r1[rt][1]; af[5]=(short)r1[rt][2];
        af[6]=(short)r1[rt][3]; af[7]=(short)r1[rt][4];
      } else if (kg == 2) {
        af[0]=(short)r1[rt][5]; af[1]=(short)r1[rt][6];
        af[2]=0; af[3]=0; af[4]=0; af[5]=0; af[6]=0; af[7]=0;
      } else {
        af[0]=0; af[1]=0; af[2]=0; af[3]=0; af[4]=0; af[5]=0; af[6]=0; af[7]=0;
      }
      #pragma unroll
      for (int nt = 0; nt < 8; nt++)
        acc[rt][nt] = __builtin_amdgcn_mfma_f32_16x16x32_bf16(af, bf[nt], acc[rt][nt], 0, 0, 0);
    }
  }
  #pragma unroll
  for (int rt = 0; rt < 2; rt++)
    #pragma unroll
    for (int nt = 0; nt < 8; nt++)
      #pragma unroll
      for (int g = 0; g < 4; g++)
        T[(rt*16 + kg*4 + g)*TS + nt*16 + cl] = f2b(silu_f(acc[rt][nt][g]));

  // ---- pe2 in two N-halves; fold pos write + o=s2*pos + att partial ----
  float ps[2][4] = {{0,0,0,0},{0,0,0,0}};
  #pragma unroll
  for (int half = 0; half < 2; half++) {
    f32x4 ph[2][4];
    #pragma unroll
    for (int n4 = 0; n4 < 4; n4++) {
      float b = bp2[(half*4 + n4)*16 + cl];
      ph[0][n4] = f32x4{b,b,b,b}; ph[1][n4] = f32x4{b,b,b,b};
    }
    #pragma unroll
    for (int kt = 0; kt < 4; kt++) {
      short8 bf[4];
      #pragma unroll
      for (int n4 = 0; n4 < 4; n4++)
        bf[n4] = *reinterpret_cast<const short8*>(wp + 81920 + ((kt*8 + half*4 + n4)*64 + lane)*8);
      #pragma unroll
      for (int rt = 0; rt < 2; rt++) {
        short8 af = *reinterpret_cast<const short8*>(T + (rt*16 + cl)*TS + kt*32 + kg*8);
        #pragma unroll
        for (int n4 = 0; n4 < 4; n4++)
          ph[rt][n4] = __builtin_amdgcn_mfma_f32_16x16x32_bf16(af, bf[n4], ph[rt][n4], 0, 0, 0);
      }
    }
    #pragma unroll
    for (int rt = 0; rt < 2; rt++)
      #pragma unroll
      for (int n4 = 0; n4 < 4; n4++) {
        int nt = half*4 + n4;
        float wa = watt[nt*16 + cl];
        #pragma unroll
        for (int g = 0; g < 4; g++) {
          float p = ph[rt][n4][g];
          pos_o[(size_t)(e0 + rt*16 + kg*4 + g) * HID + nt*16 + cl] = p;
          float o = accS[rt][nt][g] * p;
          accS[rt][nt][g] = o;
          ps[rt][g] += o * wa;
        }
      }
  }

  // ---- attention + final out ----
  float ba = batt[0];
  #pragma unroll
  for (int rt = 0; rt < 2; rt++)
    #pragma unroll
    for (int g = 0; g < 4; g++) {
      float s = ps[rt][g];
      s += __shfl_xor(s, 1);
      s += __shfl_xor(s, 2);
      s += __shfl_xor(s, 4);
      s += __shfl_xor(s, 8);
      float av = 1.0f / (1.0f + __expf(-(s + ba)));
      #pragma unroll
      for (int nt = 0; nt < 8; nt++)
        out0[(size_t)(e0 + rt*16 + kg*4 + g) * HID + nt*16 + cl] = accS[rt][nt][g] * av;
    }
}

// ---------------- launcher ----------------------------------------------------
extern "C" void kernel_launch(void* const* d_in, const int* in_sizes, int n_in,
                              void* d_out, int out_size, void* d_ws, size_t ws_size,
                              hipStream_t stream) {
  (void)in_sizes; (void)n_in; (void)out_size; (void)ws_size;
  const float* h     = (const float*)d_in[0];
  const float* coord = (const float*)d_in[1];
  const int*   edges = (const int*)d_in[2];
  const float* W_ce1 = (const float*)d_in[3];  const float* b_ce1 = (const float*)d_in[4];
  const float* W_ce2 = (const float*)d_in[5];  const float* b_ce2 = (const float*)d_in[6];
  const float* W_pe1 = (const float*)d_in[7];  const float* b_pe1 = (const float*)d_in[8];
  const float* W_pe2 = (const float*)d_in[9];  const float* b_pe2 = (const float*)d_in[10];
  const float* W_s1  = (const float*)d_in[11]; const float* b_s1  = (const float*)d_in[12];
  const float* W_s2  = (const float*)d_in[13]; const float* b_s2  = (const float*)d_in[14];
  const float* W_att = (const float*)d_in[15]; const float* b_att = (const float*)d_in[16];

  float* out  = (float*)d_out;
  float* chem = out  + (size_t)E_EDGES * HID;
  float* pos  = chem + (size_t)E_EDGES * HID;
  float* cdn  = pos  + (size_t)E_EDGES * HID;

  char* ws = (char*)d_ws;
  float* nf    = (float*)(ws);                         // NN*9 f32      (720,000 B)
  float* nvecs = (float*)(ws + 720000);                // NN*9 f32      (720,000 B)
  float* Htop  = (float*)(ws + 1440000);               // NN*128 f32    (10,240,000 B)
  float* Hbot  = (float*)(ws + 11680000);              // NN*128 f32    (10,240,000 B)
  unsigned short* wpack = (unsigned short*)(ws + 21920000);  // 102400 bf16 (204,800 B)
  unsigned short* rad16 = (unsigned short*)(ws + 22124800);  // E*16 bf16   (10,240,000 B)

  zero_k<<<(NN * 9 / 4 + 255) / 256, 256, 0, stream>>>(nf, NN * 9 / 4);
  prepack_k<<<400, 256, 0, stream>>>(W_ce1, W_ce2, W_s1, W_s2, W_pe2, W_pe1, wpack);
  node_mlp_k<<<(NN + 127) / 128, 256, 0, stream>>>(h, wpack, b_ce1, Htop, Hbot);
  edge_geom_k<<<E_EDGES / 256, 256, 0, stream>>>(edges, edges + E_EDGES, coord,
                                                 nf, cdn, rad16);
  node_norm_k<<<(NN + 255) / 256, 256, 0, stream>>>(nf, nvecs);
  chem_k<<<E_EDGES / 128, 256, 0, stream>>>(edges, edges + E_EDGES, Htop, Hbot, wpack,
                                            b_ce2, chem);
  simpos_k<<<E_EDGES / 128, 256, 0, stream>>>(edges, edges + E_EDGES, chem, rad16,
                                              nvecs, wpack, b_s1, b_s2, b_pe1, b_pe2,
                                              W_att, b_att, out, pos);
}